// Round 15
// baseline (299.570 us; speedup 1.0000x reference)
//
#include <hip/hip_runtime.h>

#define VOCAB 27
#define EMB   32
#define HID   64
#define BATCH 4096
#define TLEN  256
#define ROWS  8           // REAL batch rows per block (M=16 tile, rows 8-15 phantom)
#define TILE  16
#define WROW  96          // rnn_w row stride in floats
#define TPAD  65          // xp table row stride (floats)
#define HROW  72          // h relay row stride in ushort (144 B)

typedef __attribute__((ext_vector_type(8))) short bf16x8;
typedef __attribute__((ext_vector_type(4))) float f32x4;

// tanh(x) = 1 - 2/(exp2(2*log2e*x)+1) -- inline VALU, no libcall.
__device__ __forceinline__ float fast_tanh(float x) {
    float t = __builtin_amdgcn_exp2f(x * 2.885390081777927f);
    float r = __builtin_amdgcn_rcpf(t + 1.0f);
    return fmaf(-2.0f, r, 1.0f);
}
__device__ __forceinline__ unsigned bfbits(float f) {
    return (__float_as_uint(f) + 0x8000u) >> 16;
}

union Frag { unsigned u[4]; bf16x8 v; };

__device__ __forceinline__ f32x4 mfma16(bf16x8 a, bf16x8 b, f32x4 c) {
    return __builtin_amdgcn_mfma_f32_16x16x32_bf16(a, b, c, 0, 0, 0);
}

// LDS-only barrier: drain ds ops, NOT vmcnt (logit stores stay in flight).
__device__ __forceinline__ void lds_barrier() {
    asm volatile("s_waitcnt lgkmcnt(0)" : : : "memory");
    __builtin_amdgcn_sched_barrier(0);
    __builtin_amdgcn_s_barrier();
    __builtin_amdgcn_sched_barrier(0);
}

__global__ __launch_bounds__(256) void rnn_mfma8(
    const int*   __restrict__ X,      // (B,T)
    const float* __restrict__ emb_w,  // (27,32)
    const float* __restrict__ start,  // (1,64)
    const float* __restrict__ rnn_w,  // (64,96) [:, :32]=Wx [:, 32:]=Wh
    const float* __restrict__ rnn_b,  // (64)
    const float* __restrict__ lm_w,   // (27,64)
    const float* __restrict__ lm_b,   // (27)
    float*       __restrict__ out)    // (B,T,27)
{
    __shared__ __align__(16) float          tabf[VOCAB * TPAD];
    __shared__ __align__(16) unsigned short Hhi[2][TILE * HROW];
    __shared__ __align__(16) unsigned short Hlo[2][TILE * HROW];
    __shared__               unsigned char  tok8[TILE * TLEN];

    const int tid  = threadIdx.x;
    const int lane = tid & 63;
    const int w    = tid >> 6;       // wave id = out-hidden tile
    const int cc   = lane & 15;
    const int q    = lane >> 4;
    const int b0   = blockIdx.x * ROWS;
    const int colh = w * 16 + cc;

    // ---------------- prologue ----------------
    for (int f = tid; f < VOCAB * HID; f += 256) {
        const int v = f >> 6, i = f & 63;
        float s = rnn_b[i];
        #pragma unroll
        for (int e = 0; e < EMB; ++e)
            s = fmaf(rnn_w[i * WROW + e], emb_w[v * EMB + e], s);
        tabf[v * TPAD + i] = s;
    }
    for (int idx = tid; idx < TILE * TLEN; idx += 256) {
        const int r = idx >> 8, t = idx & 255;
        tok8[idx] = (r < ROWS)
            ? (unsigned char)X[(size_t)(b0 + r) * TLEN + t] : (unsigned char)0;
    }
    for (int idx = tid; idx < TILE * HID; idx += 256) {
        const int r = idx >> 6, j = idx & 63;
        const float s = start[j];            // phantom rows get start too (finite)
        const unsigned hb = bfbits(s);
        Hhi[1][r * HROW + j] = (unsigned short)hb;
        Hlo[1][r * HROW + j] = (unsigned short)bfbits(s - __uint_as_float(hb << 16));
    }

    // Wh^T B-fragments, hi/lo split (layout proven R9/R13).
    Frag whh[2], whl[2];
    #pragma unroll
    for (int kc = 0; kc < 2; ++kc) {
        const float* wr = &rnn_w[colh * WROW + EMB + q * 8 + kc * 32];
        #pragma unroll
        for (int p = 0; p < 4; ++p) {
            const float w0 = wr[2 * p], w1 = wr[2 * p + 1];
            const unsigned h0 = bfbits(w0), h1 = bfbits(w1);
            whh[kc].u[p] = h0 | (h1 << 16);
            whl[kc].u[p] = bfbits(w0 - __uint_as_float(h0 << 16)) |
                           (bfbits(w1 - __uint_as_float(h1 << 16)) << 16);
        }
    }
    // lm_w^T B-fragments on waves 2,3.
    Frag lwh[2], lwl[2];
    float lb = 0.0f;
    if (w >= 2) {
        const int  v  = (w - 2) * 16 + cc;
        const bool ok = v < VOCAB;
        #pragma unroll
        for (int kc = 0; kc < 2; ++kc) {
            const float* wr = &lm_w[(ok ? v : 0) * HID + q * 8 + kc * 32];
            #pragma unroll
            for (int p = 0; p < 4; ++p) {
                const float w0 = ok ? wr[2 * p] : 0.0f;
                const float w1 = ok ? wr[2 * p + 1] : 0.0f;
                const unsigned h0 = bfbits(w0), h1 = bfbits(w1);
                lwh[kc].u[p] = h0 | (h1 << 16);
                lwl[kc].u[p] = bfbits(w0 - __uint_as_float(h0 << 16)) |
                               (bfbits(w1 - __uint_as_float(h1 << 16)) << 16);
            }
        }
        lb = ok ? lm_b[v] : 0.0f;
    }

    __syncthreads();   // prologue barrier (full drain fine, once)

    Frag ah[2], al[2];
    #pragma unroll
    for (int kc = 0; kc < 2; ++kc) {
        ah[kc].v = *(const bf16x8*)&Hhi[1][cc * HROW + q * 8 + kc * 32];
        al[kc].v = *(const bf16x8*)&Hlo[1][cc * HROW + q * 8 + kc * 32];
    }
    int   tkn[4];
    float xq[4];
    #pragma unroll
    for (int r = 0; r < 4; ++r) {
        tkn[r] = tok8[(4 * q + r) * TLEN];
        xq[r]  = tabf[tkn[r] * TPAD + colh];
    }

    // ---------------- main loop ----------------
    for (int t = 0; t < TLEN; ++t) {
        const int tn = (t + 1) & (TLEN - 1);
        #pragma unroll
        for (int r = 0; r < 4; ++r)
            tkn[r] = tok8[(4 * q + r) * TLEN + tn];

        // rec on h_{t-1} frags: 3 independent depth-2 MFMA chains
        f32x4 a0 = {xq[0], xq[1], xq[2], xq[3]};
        f32x4 a1 = {0.0f, 0.0f, 0.0f, 0.0f};
        f32x4 a2 = {0.0f, 0.0f, 0.0f, 0.0f};
        a0 = mfma16(ah[0].v, whh[0].v, a0); a0 = mfma16(ah[1].v, whh[1].v, a0);
        a1 = mfma16(al[0].v, whh[0].v, a1); a1 = mfma16(al[1].v, whh[1].v, a1);
        a2 = mfma16(ah[0].v, whl[0].v, a2); a2 = mfma16(ah[1].v, whl[1].v, a2);

        // h_t publish (pre-split bf16 hi/lo)
        const int buf = t & 1;
        #pragma unroll
        for (int r = 0; r < 4; ++r) {
            const float hv = fast_tanh((a0[r] + a1[r]) + a2[r]);
            const unsigned hb = bfbits(hv);
            Hhi[buf][(4 * q + r) * HROW + colh] = (unsigned short)hb;
            Hlo[buf][(4 * q + r) * HROW + colh] =
                (unsigned short)bfbits(hv - __uint_as_float(hb << 16));
        }

        // deferred logits of h_{t-1}: frags still live; fills barrier slack
        f32x4 g0 = {0.0f, 0.0f, 0.0f, 0.0f};
        f32x4 g1 = {0.0f, 0.0f, 0.0f, 0.0f};
        f32x4 g2 = {0.0f, 0.0f, 0.0f, 0.0f};
        if (w >= 2 && t > 0) {
            g0 = (f32x4){lb, lb, lb, lb};
            g0 = mfma16(ah[0].v, lwh[0].v, g0); g0 = mfma16(ah[1].v, lwh[1].v, g0);
            g1 = mfma16(al[0].v, lwh[0].v, g1); g1 = mfma16(al[1].v, lwh[1].v, g1);
            g2 = mfma16(ah[0].v, lwl[0].v, g2); g2 = mfma16(ah[1].v, lwl[1].v, g2);
        }

        lds_barrier();   // lgkmcnt only; logit stores from prev iter stay in flight

        #pragma unroll
        for (int kc = 0; kc < 2; ++kc) {
            ah[kc].v = *(const bf16x8*)&Hhi[buf][cc * HROW + q * 8 + kc * 32];
            al[kc].v = *(const bf16x8*)&Hlo[buf][cc * HROW + q * 8 + kc * 32];
        }
        #pragma unroll
        for (int r = 0; r < 4; ++r)
            xq[r] = tabf[tkn[r] * TPAD + colh];

        if (w >= 2 && t > 0) {
            const int col = (w - 2) * 16 + cc;
            if (col < VOCAB) {
                const size_t base =
                    ((size_t)(b0 + 4 * q) * TLEN + (t - 1)) * VOCAB + col;
                #pragma unroll
                for (int r = 0; r < 4; ++r)
                    if (4 * q + r < ROWS)
                        out[base + (size_t)r * (TLEN * VOCAB)] =
                            (g0[r] + g1[r]) + g2[r];
            }
        }
    }

    // epilogue: logits of h_{T-1}
    if (w >= 2) {
        f32x4 g0 = {lb, lb, lb, lb};
        f32x4 g1 = {0.0f, 0.0f, 0.0f, 0.0f};
        f32x4 g2 = {0.0f, 0.0f, 0.0f, 0.0f};
        g0 = mfma16(ah[0].v, lwh[0].v, g0); g0 = mfma16(ah[1].v, lwh[1].v, g0);
        g1 = mfma16(al[0].v, lwh[0].v, g1); g1 = mfma16(al[1].v, lwh[1].v, g1);
        g2 = mfma16(ah[0].v, lwl[0].v, g2); g2 = mfma16(ah[1].v, lwl[1].v, g2);
        const int col = (w - 2) * 16 + cc;
        if (col < VOCAB) {
            const size_t base =
                ((size_t)(b0 + 4 * q) * TLEN + (TLEN - 1)) * VOCAB + col;
            #pragma unroll
            for (int r = 0; r < 4; ++r)
                if (4 * q + r < ROWS)
                    out[base + (size_t)r * (TLEN * VOCAB)] =
                        (g0[r] + g1[r]) + g2[r];
        }
    }
}

extern "C" void kernel_launch(void* const* d_in, const int* in_sizes, int n_in,
                              void* d_out, int out_size, void* d_ws, size_t ws_size,
                              hipStream_t stream) {
    const int*   X     = (const int*)  d_in[0];
    const float* emb_w = (const float*)d_in[1];
    const float* start = (const float*)d_in[2];
    const float* rnn_w = (const float*)d_in[3];
    const float* rnn_b = (const float*)d_in[4];
    const float* lm_w  = (const float*)d_in[5];
    const float* lm_b  = (const float*)d_in[6];
    float*       out   = (float*)d_out;

    dim3 grid(BATCH / ROWS);   // 512 blocks: 8 real rows each, 2 blocks/CU
    dim3 block(256);
    rnn_mfma8<<<grid, block, 0, stream>>>(X, emb_w, start, rnn_w, rnn_b,
                                          lm_w, lm_b, out);
}